// Round 2
// baseline (157.362 us; speedup 1.0000x reference)
//
#include <hip/hip_runtime.h>

#define LL   8192   // sequence length
#define CC   2048   // channels
#define FF   128    // inner dim of g@kernel
#define KK   257    // taps
#define PAD  128    // (KK-1)/2

#define SROWP 328   // synEb row stride (u16): 32 zeros | 257 taps | 31 zeros | 8 pad (164 dw)
#define NT   18     // K-steps of 16 -> covers K in [0,288)
#define NCH  8      // channels per block
#define NW   4      // windows (1024 outputs each) per block
#define ROWS 1288   // xch row in u16 = 644 dwords == 4 (mod 32 banks) -> conflict-free writes

typedef __bf16 bf16x8 __attribute__((ext_vector_type(8)));
typedef float  f32x16 __attribute__((ext_vector_type(16)));

static __device__ __forceinline__ unsigned short f2bf(float f) {
    unsigned u = __float_as_uint(f);
    u = (u + 0x7fffu + ((u >> 16) & 1u)) >> 16;   // RNE
    return (unsigned short)u;
}

// Build synEb[c][328] bf16: zeros | g[c,:]@kernel[:,k] | zeros (incl. pad), with the
// Yt-row override folded in as a delta kernel (tap=1 at k=128).
__global__ __launch_bounds__(256) void synb_kernel(const float* __restrict__ g,
                                                   const float* __restrict__ kern,
                                                   const int* __restrict__ Yt, int ny,
                                                   unsigned short* __restrict__ synEb) {
    __shared__ int sfl[4];
    const int c0 = blockIdx.x * 4;
    const int t  = threadIdx.x;
    if (t < 4) sfl[t] = 0;
    __syncthreads();
    for (int i = t; i < ny; i += 256) {
        int y = Yt[i];
        #pragma unroll
        for (int ii = 0; ii < 4; ++ii) if (y == c0 + ii) sfl[ii] = 1;
    }
    __syncthreads();
    const float* g0 = g + (size_t)(c0 + 0) * FF;
    const float* g1 = g + (size_t)(c0 + 1) * FF;
    const float* g2 = g + (size_t)(c0 + 2) * FF;
    const float* g3 = g + (size_t)(c0 + 3) * FF;
    const int fl0 = sfl[0], fl1 = sfl[1], fl2 = sfl[2], fl3 = sfl[3];
    for (int p = t; p < SROWP; p += 256) {
        const int kk = p - 32;
        float a0 = 0.f, a1 = 0.f, a2 = 0.f, a3 = 0.f;
        const bool inr = (kk >= 0) && (kk < KK);
        if (inr) {
            #pragma unroll 8
            for (int f = 0; f < FF; ++f) {
                float kv = kern[f * KK + kk];      // coalesced across p
                a0 += kv * g0[f];
                a1 += kv * g1[f];
                a2 += kv * g2[f];
                a3 += kv * g3[f];
            }
        }
        float dlt = (kk == PAD) ? 1.f : 0.f;
        float v0 = inr ? (fl0 ? dlt : a0) : 0.f;
        float v1 = inr ? (fl1 ? dlt : a1) : 0.f;
        float v2 = inr ? (fl2 ? dlt : a2) : 0.f;
        float v3 = inr ? (fl3 ? dlt : a3) : 0.f;
        synEb[(size_t)(c0 + 0) * SROWP + p] = f2bf(v0);
        synEb[(size_t)(c0 + 1) * SROWP + p] = f2bf(v1);
        synEb[(size_t)(c0 + 2) * SROWP + p] = f2bf(v2);
        synEb[(size_t)(c0 + 3) * SROWP + p] = f2bf(v3);
    }
}

// ---- staging helpers: T14 async split (issue-early global->reg, write-late reg->LDS) ----
static __device__ __forceinline__ void stage_issue(const float* __restrict__ x,
                                                   int W0, int c0, int t,
                                                   float4* ev, float4* ov) {
    #pragma unroll
    for (int k = 0; k < 5; ++k) {
        int pidx = (k << 8) + t;              // [0,1280)
        int ch4  = pidx & 1;                  // which 4-channel half of 8
        int pp   = pidx >> 1;                 // l-pair index [0,640)
        int lg   = W0 + (pp << 1) - 128;      // global l of even element
        const float* sp = x + (size_t)lg * CC + c0 + (ch4 << 2);
        float4 a = make_float4(0.f, 0.f, 0.f, 0.f);
        float4 b = make_float4(0.f, 0.f, 0.f, 0.f);
        if ((unsigned)lg       < (unsigned)LL) a = *(const float4*)sp;
        if ((unsigned)(lg + 1) < (unsigned)LL) b = *(const float4*)(sp + CC);
        ev[k] = a; ov[k] = b;
    }
}

static __device__ __forceinline__ void stage_write(unsigned short (*buf)[ROWS], int t,
                                                   const float4* ev, const float4* ov) {
    #pragma unroll
    for (int k = 0; k < 5; ++k) {
        int pidx = (k << 8) + t;
        int ch4  = pidx & 1;
        int pp   = pidx >> 1;
        int gq   = pp >> 2;                   // granule (8 u16)
        int gp   = gq ^ ((gq >> 3) & 7);      // XOR swizzle (verified layout)
        int dw   = (gp << 2) | (pp & 3);      // dword slot within row
        const float* pe = (const float*)&ev[k];
        const float* po = (const float*)&ov[k];
        #pragma unroll
        for (int c2 = 0; c2 < 4; ++c2) {
            unsigned val = (unsigned)f2bf(pe[c2]) | ((unsigned)f2bf(po[c2]) << 16);
            ((unsigned*)buf[(ch4 << 2) + c2])[dw] = val;
        }
    }
}

// Persistent double-buffered fused transpose + depthwise Toeplitz-MFMA conv.
// Block: 8 channels x 4 windows of 1024 outputs. Per window: issue next window's
// global loads into regs, compute current window from LDS (2ch/wave x 18 MFMA),
// then convert+write the staged regs into the other LDS buffer. HBM read latency
// hides under compute; 512 blocks = 2/CU exactly (46.5 KB LDS), zero tail.
__global__ __launch_bounds__(256, 2) void fused_conv(const float* __restrict__ x,
                                                     const unsigned short* __restrict__ synEb,
                                                     float* __restrict__ out) {
    __shared__ alignas(16) unsigned short xch[2][NCH][ROWS];  // 41,216 B
    __shared__ alignas(16) unsigned short synL[NCH][SROWP];   //  5,248 B
    const int t = threadIdx.x;

    // XCD-chunked remap: the 8 blocks {y in [4g,4g+4), x in {0,1}} share x cache
    // lines; give them dispatch indices == g (mod 8) so round-robin puts them on
    // one XCD's L2. Bijective on [0,512).
    const int d    = (blockIdx.y << 1) | blockIdx.x;  // linear dispatch id [0,512)
    const int grp  = ((d >> 6) << 3) | (d & 7);       // [0,64)
    const int rnk  = (d >> 3) & 7;                    // [0,8)
    const int cg   = (grp << 2) | (rnk >> 1);         // channel group [0,256)
    const int bx   = rnk & 1;                         // L-half {0,1}
    const int c0 = cg << 3;
    const int L0 = bx << 12;                          // bx * 4096

    // ---- stage synL once (amortized over 4 windows): 8 rows x 164 dwords ----
    {
        const int rr = t >> 5, u0 = t & 31;
        const unsigned* src = (const unsigned*)(synEb + (size_t)(c0 + rr) * SROWP);
        unsigned* dst = (unsigned*)synL[rr];
        for (int u = u0; u < SROWP / 2; u += 32) dst[u] = src[u];
    }

    const int w_id = t >> 6, ln = t & 63;
    const int j = ln & 31, q = ln >> 5;
    const int bb  = (q << 4) - 2 * j + 64;    // byte base of bfrag m=0 (in [2,80], even)
    const int dwb = bb >> 2;                  // dword base at m=0 (in [0,20])
    const int sh  = (bb & 2) << 3;            // residual funnel shift: 0 or 16 bits
    const int gb  = (j << 2) + q;             // A granule base

    // ---- prologue: fill buf0 with window 0 ----
    float4 ev[5], ov[5];
    stage_issue(x, L0, c0, t, ev, ov);
    stage_write(xch[0], t, ev, ov);
    __syncthreads();

    for (int w = 0; w < NW; ++w) {
        const int cur = w & 1;
        const int W0  = L0 + (w << 10);
        // issue next window's loads BEFORE compute (latency hides under MFMA+stores)
        if (w + 1 < NW) stage_issue(x, W0 + 1024, c0, t, ev, ov);

        // ---- compute window w from xch[cur] ----
        #pragma unroll
        for (int cc = 0; cc < 2; ++cc) {
            const int ci = (w_id << 1) + cc;
            const unsigned* rp = (const unsigned*)(synL[ci]) + dwb;
            f32x16 acc;
            #pragma unroll
            for (int r = 0; r < 16; ++r) acc[r] = 0.f;
            #pragma unroll
            for (int m = 0; m < NT; ++m) {
                // B: 5 LDS dwords + 64-bit funnel by sh (v_alignbit).
                // u16 index (16m + 8q + r - j + 32); max dword = dwb+140+4 <= 164. OK.
                unsigned w0 = rp[(m << 3) + 0], w1 = rp[(m << 3) + 1], w2 = rp[(m << 3) + 2],
                         w3 = rp[(m << 3) + 3], w4 = rp[(m << 3) + 4];
                union { unsigned dd[4]; bf16x8 v; } B;
                B.dd[0] = (unsigned)((((unsigned long long)w1 << 32) | w0) >> sh);
                B.dd[1] = (unsigned)((((unsigned long long)w2 << 32) | w1) >> sh);
                B.dd[2] = (unsigned)((((unsigned long long)w3 << 32) | w2) >> sh);
                B.dd[3] = (unsigned)((((unsigned long long)w4 << 32) | w3) >> sh);
                int gq2 = gb + (m << 1);
                int gp2 = gq2 ^ ((gq2 >> 3) & 7);
                union { int4 i4; bf16x8 v; } A;
                A.i4 = *(const int4*)(&xch[cur][ci][gp2 << 3]);
                acc = __builtin_amdgcn_mfma_f32_32x32x16_bf16(A.v, B.v, acc, 0, 0, 0);
            }
            // ---- store: D col=lane&31, row=(r&3)+8*(r>>2)+4q ----
            float* o = out + (size_t)(c0 + ci) * LL + W0 + j;
            #pragma unroll
            for (int r = 0; r < 16; ++r) {
                int row = (r & 3) + ((r >> 2) << 3) + (q << 2);
                o[row << 5] = acc[r];         // 2 x 128B segments per instr
            }
        }
        __syncthreads();                      // all waves done reading xch[cur]
        // write-late: staged regs -> other buffer (vmcnt satisfied under compute)
        if (w + 1 < NW) stage_write(xch[cur ^ 1], t, ev, ov);
        __syncthreads();
    }
}

// ------------------------------------------------------------------- launch
extern "C" void kernel_launch(void* const* d_in, const int* in_sizes, int n_in,
                              void* d_out, int out_size, void* d_ws, size_t ws_size,
                              hipStream_t stream) {
    const float* x    = (const float*)d_in[0];
    const int*   Yt   = (const int*)  d_in[1];
    const float* g    = (const float*)d_in[2];
    const float* kern = (const float*)d_in[3];
    float* out = (float*)d_out;
    const int ny = in_sizes[1];

    unsigned short* synEb = (unsigned short*)d_ws;   // 2048*328*2 = 1.34 MB

    synb_kernel<<<CC / 4, 256, 0, stream>>>(g, kern, Yt, ny, synEb);
    fused_conv<<<dim3(2, 256), 256, 0, stream>>>(x, synEb, out);
}

// Round 3
// 155.332 us; speedup vs baseline: 1.0131x; 1.0131x over previous
//
#include <hip/hip_runtime.h>

#define LL   8192   // sequence length
#define CC   2048   // channels
#define FF   128    // inner dim of g@kernel
#define KK   257    // taps
#define PAD  128    // (KK-1)/2

#define SROWP 328   // synEb row stride (u16): 32 zeros | 257 taps | 31 zeros | 8 pad (164 dw)
#define NT   18     // K-steps of 16 -> covers K in [0,288)
#define NCH  8      // channels per block = waves per block (1 wave : 1 channel)
#define NW   8      // windows (1024 outputs) per block -> full L per block
#define ROWS 1288   // xch row in u16 = 644 dwords == 4 (mod 32 banks) -> conflict-free writes

typedef __bf16 bf16x8 __attribute__((ext_vector_type(8)));
typedef float  f32x16 __attribute__((ext_vector_type(16)));

static __device__ __forceinline__ unsigned short f2bf(float f) {
    unsigned u = __float_as_uint(f);
    u = (u + 0x7fffu + ((u >> 16) & 1u)) >> 16;   // RNE
    return (unsigned short)u;
}

// Build synEb[c][328] bf16: zeros | g[c,:]@kernel[:,k] | zeros (incl. pad), with the
// Yt-row override folded in as a delta kernel (tap=1 at k=128).
__global__ __launch_bounds__(256) void synb_kernel(const float* __restrict__ g,
                                                   const float* __restrict__ kern,
                                                   const int* __restrict__ Yt, int ny,
                                                   unsigned short* __restrict__ synEb) {
    __shared__ int sfl[4];
    const int c0 = blockIdx.x * 4;
    const int t  = threadIdx.x;
    if (t < 4) sfl[t] = 0;
    __syncthreads();
    for (int i = t; i < ny; i += 256) {
        int y = Yt[i];
        #pragma unroll
        for (int ii = 0; ii < 4; ++ii) if (y == c0 + ii) sfl[ii] = 1;
    }
    __syncthreads();
    const float* g0 = g + (size_t)(c0 + 0) * FF;
    const float* g1 = g + (size_t)(c0 + 1) * FF;
    const float* g2 = g + (size_t)(c0 + 2) * FF;
    const float* g3 = g + (size_t)(c0 + 3) * FF;
    const int fl0 = sfl[0], fl1 = sfl[1], fl2 = sfl[2], fl3 = sfl[3];
    for (int p = t; p < SROWP; p += 256) {
        const int kk = p - 32;
        float a0 = 0.f, a1 = 0.f, a2 = 0.f, a3 = 0.f;
        const bool inr = (kk >= 0) && (kk < KK);
        if (inr) {
            #pragma unroll 8
            for (int f = 0; f < FF; ++f) {
                float kv = kern[f * KK + kk];      // coalesced across p
                a0 += kv * g0[f];
                a1 += kv * g1[f];
                a2 += kv * g2[f];
                a3 += kv * g3[f];
            }
        }
        float dlt = (kk == PAD) ? 1.f : 0.f;
        float v0 = inr ? (fl0 ? dlt : a0) : 0.f;
        float v1 = inr ? (fl1 ? dlt : a1) : 0.f;
        float v2 = inr ? (fl2 ? dlt : a2) : 0.f;
        float v3 = inr ? (fl3 ? dlt : a3) : 0.f;
        synEb[(size_t)(c0 + 0) * SROWP + p] = f2bf(v0);
        synEb[(size_t)(c0 + 1) * SROWP + p] = f2bf(v1);
        synEb[(size_t)(c0 + 2) * SROWP + p] = f2bf(v2);
        synEb[(size_t)(c0 + 3) * SROWP + p] = f2bf(v3);
    }
}

// ---- staging helpers (512 threads, 8 channels, float2 = 2ch per lane) ----
// T14 async split: issue-early global->reg, write-late reg->LDS.
static __device__ __forceinline__ void stage_issue(const float* __restrict__ x,
                                                   int W0, int c0, int t,
                                                   float2* ev, float2* ov) {
    #pragma unroll
    for (int k = 0; k < 5; ++k) {
        int pidx = (k << 9) + t;              // [0,2560)
        int ch2  = pidx & 3;                  // channel pair (2 of 8)
        int pp   = pidx >> 2;                 // l-pair index [0,640)
        int lg   = W0 + (pp << 1) - 128;      // global l of even element
        const float* sp = x + (size_t)lg * CC + c0 + (ch2 << 1);
        float2 a = make_float2(0.f, 0.f);
        float2 b = make_float2(0.f, 0.f);
        if ((unsigned)lg       < (unsigned)LL) a = *(const float2*)sp;
        if ((unsigned)(lg + 1) < (unsigned)LL) b = *(const float2*)(sp + CC);
        ev[k] = a; ov[k] = b;
    }
}

static __device__ __forceinline__ void stage_write(unsigned short (*buf)[ROWS], int t,
                                                   const float2* ev, const float2* ov) {
    #pragma unroll
    for (int k = 0; k < 5; ++k) {
        int pidx = (k << 9) + t;
        int ch2  = pidx & 3;
        int pp   = pidx >> 2;
        int gq   = pp >> 2;                   // granule (8 u16)
        int gp   = gq ^ ((gq >> 3) & 7);      // XOR swizzle (verified layout)
        int dw   = (gp << 2) | (pp & 3);      // dword slot within row
        const float* pe = (const float*)&ev[k];
        const float* po = (const float*)&ov[k];
        #pragma unroll
        for (int c2 = 0; c2 < 2; ++c2) {
            unsigned val = (unsigned)f2bf(pe[c2]) | ((unsigned)f2bf(po[c2]) << 16);
            ((unsigned*)buf[(ch2 << 1) + c2])[dw] = val;
        }
    }
}

// Persistent fused transpose + depthwise Toeplitz-MFMA conv.
// Block: 512 threads / 8 waves; 1 wave = 1 channel; 8 windows = full L.
// B-fragments (window-invariant!) are built ONCE per block into 72 VGPRs;
// the per-window inner loop is {ds_read_b128 A + MFMA} x 18 with precomputed
// swizzled offsets. x staging: issue next window's float2 loads before compute,
// convert+write after the barrier (HBM latency hides under compute+stores).
// Grid = 256 = exactly 1 block/CU, zero tail.
__global__ __launch_bounds__(512, 2) void fused_conv(const float* __restrict__ x,
                                                     const unsigned short* __restrict__ synEb,
                                                     float* __restrict__ out) {
    __shared__ alignas(16) unsigned short xch[2][NCH][ROWS];  // 41,216 B
    __shared__ alignas(16) unsigned short synL[NCH][SROWP];   //  5,248 B
    const int t = threadIdx.x;

    // XCD-contiguous channel slabs: dispatch d lands on XCD d%8 (round-robin);
    // give XCD k the contiguous channel-groups [32k, 32k+32) so the 32B/block
    // column slices of each x row merge into full cache lines within one L2.
    const int d  = blockIdx.x;                 // [0,256)
    const int cg = ((d & 7) << 5) | (d >> 3);  // bijective on [0,256)
    const int c0 = cg << 3;

    const int ci = t >> 6;                     // wave id = channel index [0,8)
    const int ln = t & 63;
    const int j = ln & 31, q = ln >> 5;
    const int bb  = (q << 4) - 2 * j + 64;     // byte base of bfrag m=0 (in [2,80], even)
    const int dwb = bb >> 2;                   // dword base at m=0 (in [0,20])
    const int sh  = (bb & 2) << 3;             // residual funnel shift: 0 or 16 bits
    const int gb  = (j << 2) + q;              // A granule base

    // ---- issue window-0 x loads first: HBM latency hides under B setup ----
    float2 ev[5], ov[5];
    stage_issue(x, 0, c0, t, ev, ov);

    // ---- stage synL (8 rows x 164 dwords, coalesced, once) ----
    for (int u = t; u < NCH * (SROWP / 2); u += 512) {
        int rr = u / (SROWP / 2), uu = u - rr * (SROWP / 2);
        ((unsigned*)synL[rr])[uu] =
            ((const unsigned*)(synEb + (size_t)(c0 + rr) * SROWP))[uu];
    }
    __syncthreads();

    // ---- build B fragments ONCE (window-invariant): 18 x bf16x8 = 72 VGPR ----
    bf16x8 bfrag[NT];
    {
        const unsigned* rp = (const unsigned*)(synL[ci]) + dwb;
        #pragma unroll
        for (int m = 0; m < NT; ++m) {
            // B.u16[r] = synL[ci][16m + 8q + r - j + 32]; max dword = dwb+140+4 <= 160 < 164.
            unsigned w0 = rp[(m << 3) + 0], w1 = rp[(m << 3) + 1], w2 = rp[(m << 3) + 2],
                     w3 = rp[(m << 3) + 3], w4 = rp[(m << 3) + 4];
            union { unsigned dd[4]; bf16x8 v; } B;
            B.dd[0] = (unsigned)((((unsigned long long)w1 << 32) | w0) >> sh);
            B.dd[1] = (unsigned)((((unsigned long long)w2 << 32) | w1) >> sh);
            B.dd[2] = (unsigned)((((unsigned long long)w3 << 32) | w2) >> sh);
            B.dd[3] = (unsigned)((((unsigned long long)w4 << 32) | w3) >> sh);
            bfrag[m] = B.v;
        }
    }

    // ---- precompute swizzled A byte offsets (per-lane, window-invariant) ----
    int aoff[NT];
    #pragma unroll
    for (int m = 0; m < NT; ++m) {
        int gq2 = gb + (m << 1);
        int gp2 = gq2 ^ ((gq2 >> 3) & 7);
        aoff[m] = gp2 << 4;                    // byte offset within row
    }

    // ---- prologue: write window 0 into buf 0 ----
    stage_write(xch[0], t, ev, ov);
    __syncthreads();

    for (int w = 0; w < NW; ++w) {
        const int cur = w & 1;
        const int W0  = w << 10;
        // issue next window's loads BEFORE compute (latency hides under MFMA+stores)
        if (w + 1 < NW) stage_issue(x, W0 + 1024, c0, t, ev, ov);

        // ---- compute: 18 x {ds_read_b128 + MFMA}, B already in regs ----
        const char* xrow = (const char*)xch[cur][ci];
        f32x16 acc;
        #pragma unroll
        for (int r = 0; r < 16; ++r) acc[r] = 0.f;
        #pragma unroll
        for (int m = 0; m < NT; ++m) {
            union { int4 i4; bf16x8 v; } A;
            A.i4 = *(const int4*)(xrow + aoff[m]);
            acc = __builtin_amdgcn_mfma_f32_32x32x16_bf16(A.v, bfrag[m], acc, 0, 0, 0);
        }
        // ---- store: D col=lane&31, row=(r&3)+8*(r>>2)+4q ----
        float* o = out + (size_t)(c0 + ci) * LL + W0 + j;
        #pragma unroll
        for (int r = 0; r < 16; ++r) {
            int row = (r & 3) + ((r >> 2) << 3) + (q << 2);
            o[row << 5] = acc[r];              // 2 x 128B segments per instr
        }
        __syncthreads();                       // all waves done reading xch[cur]
        // write-late: staged regs -> other buffer (vmcnt satisfied under compute)
        if (w + 1 < NW) stage_write(xch[cur ^ 1], t, ev, ov);
        __syncthreads();
    }
}

// ------------------------------------------------------------------- launch
extern "C" void kernel_launch(void* const* d_in, const int* in_sizes, int n_in,
                              void* d_out, int out_size, void* d_ws, size_t ws_size,
                              hipStream_t stream) {
    const float* x    = (const float*)d_in[0];
    const int*   Yt   = (const int*)  d_in[1];
    const float* g    = (const float*)d_in[2];
    const float* kern = (const float*)d_in[3];
    float* out = (float*)d_out;
    const int ny = in_sizes[1];

    unsigned short* synEb = (unsigned short*)d_ws;   // 2048*328*2 = 1.34 MB

    synb_kernel<<<CC / 4, 256, 0, stream>>>(g, kern, Yt, ny, synEb);
    fused_conv<<<256, 512, 0, stream>>>(x, synEb, out);
}